// Round 8
// baseline (547.043 us; speedup 1.0000x reference)
//
#include <hip/hip_runtime.h>
#include <hip/hip_bf16.h>
#include <cstdint>
#include <cstddef>

// Problem constants (T5 self-attention, B=2, S=2048, H=16, D=64, d_model=1024)
#define S_LEN 2048
#define NH 16
#define DKV 64
#define BATCH 2
#define DMODEL 1024

typedef _Float16 half_t;
typedef __attribute__((ext_vector_type(4))) _Float16 halfx4;  // 8 B
typedef __attribute__((ext_vector_type(8))) _Float16 half8;   // MFMA A/B frag (4 VGPRs)
typedef __attribute__((ext_vector_type(4))) float floatx4;    // MFMA C/D frag

// async global->LDS, 16 B per lane; LDS dest = wave-uniform base + lane*16
__device__ __forceinline__ void load_lds16(const half_t* g, half_t* l) {
  __builtin_amdgcn_global_load_lds((const __attribute__((address_space(1))) void*)g,
                                   (__attribute__((address_space(3))) void*)l, 16, 0, 0);
}

// max-reduce over 16 lanes (l15 within quad) via ds_swizzle xor 1,2,4,8
__device__ __forceinline__ float qmax16(float v) {
  int i;
  i = __builtin_amdgcn_ds_swizzle(__float_as_int(v), 0x041F); v = fmaxf(v, __int_as_float(i));
  i = __builtin_amdgcn_ds_swizzle(__float_as_int(v), 0x081F); v = fmaxf(v, __int_as_float(i));
  i = __builtin_amdgcn_ds_swizzle(__float_as_int(v), 0x101F); v = fmaxf(v, __int_as_float(i));
  i = __builtin_amdgcn_ds_swizzle(__float_as_int(v), 0x201F); v = fmaxf(v, __int_as_float(i));
  return v;
}

// ---------------------------------------------------------------------------
// T5 relative-position bucket — EXACT integer thresholds (ceil(8*16^(n/8))),
// verified to agree with the fp32 reference at every integer delta.
// Capped for |delta| >= 91 -> 183-entry table covers all deltas.
// ---------------------------------------------------------------------------
__device__ __forceinline__ int t5_bucket(int delta) {
  int base = (delta > 0) ? 16 : 0;
  int a = delta < 0 ? -delta : delta;
  int n;
  if (a < 8)       n = a;
  else if (a < 12) n = 8;
  else if (a < 16) n = 9;
  else if (a < 23) n = 10;
  else if (a < 32) n = 11;
  else if (a < 46) n = 12;
  else if (a < 64) n = 13;
  else if (a < 91) n = 14;
  else             n = 15;
  return base + n;
}

// ---------------------------------------------------------------------------
// Fused prep: fp32->fp16 cast of hidden (blocks 0..4095), w_qkv transpose-cast
// (blocks 4096..7167), w_o transpose-cast (blocks 7168..8191). All independent
// memory-bound work in one dispatch (saves 2 launches).
// ---------------------------------------------------------------------------
__global__ __launch_bounds__(256) void prep_kernel(const float* __restrict__ hidden,
                                                   const float* __restrict__ w_qkv,
                                                   const float* __restrict__ w_o,
                                                   half_t* __restrict__ Ah,
                                                   half_t* __restrict__ Wqt,
                                                   half_t* __restrict__ Wot) {
  __shared__ float t[32][33];
  const int bx = blockIdx.x;
  if (bx < 4096) {
    int i = bx * 256 + threadIdx.x;
    float4 v = ((const float4*)hidden)[i];
    halfx4 h;
    h[0] = (half_t)v.x; h[1] = (half_t)v.y; h[2] = (half_t)v.z; h[3] = (half_t)v.w;
    ((halfx4*)Ah)[i] = h;
    return;
  }
  const float* in;
  half_t* out;
  int R, C, bb;
  if (bx < 4096 + 3072) {
    bb = bx - 4096; in = w_qkv; out = Wqt; R = 1024; C = 3072;
  } else {
    bb = bx - 7168; in = w_o; out = Wot; R = 1024; C = 1024;
  }
  const int ct = C / 32;
  const int c0 = (bb % ct) * 32, r0 = (bb / ct) * 32;
  const int lr = threadIdx.x >> 3;
  const int lc = (threadIdx.x & 7) * 4;
  float4 v = *(const float4*)(in + (size_t)(r0 + lr) * C + c0 + lc);
  t[lr][lc + 0] = v.x; t[lr][lc + 1] = v.y; t[lr][lc + 2] = v.z; t[lr][lc + 3] = v.w;
  __syncthreads();
  halfx4 hv;
#pragma unroll
  for (int u = 0; u < 4; u++) hv[u] = (half_t)t[lc + u][lr];
  *(halfx4*)(out + (size_t)(c0 + lr) * R + r0 + lc) = hv;
}

// ---------------------------------------------------------------------------
// fp16 [b,h,s,d] -> [b,h,d,s] transpose (V). 64x64 tile per block.
// ---------------------------------------------------------------------------
__global__ __launch_bounds__(256) void vtrans(const half_t* __restrict__ V,
                                              half_t* __restrict__ Vt) {
  __shared__ half_t T[64 * 72];
  const int bh = blockIdx.y;
  const int s0 = blockIdx.x * 64;
  const half_t* src = V + ((size_t)bh * S_LEN + s0) * DKV;
  half_t* dst = Vt + (size_t)bh * DKV * S_LEN + s0;
  const int sr = threadIdx.x >> 3;        // 0..31
  const int dc = (threadIdx.x & 7) * 8;   // 0..56
#pragma unroll
  for (int p = 0; p < 2; p++) {
    int s = sr + p * 32;
    half8 v = *(const half8*)(src + (size_t)s * DKV + dc);
#pragma unroll
    for (int u = 0; u < 8; u++) T[(dc + u) * 72 + s] = v[u];
  }
  __syncthreads();
#pragma unroll
  for (int p = 0; p < 2; p++) {
    int d = sr + p * 32;
    half8 v = *(half8*)&T[d * 72 + dc];
    *(half8*)(dst + (size_t)d * S_LEN + dc) = v;
  }
}

// ---------------------------------------------------------------------------
// FUSED: QKV fp16 MFMA GEMM (blocks 0..767) + position_bias writer (768..1279).
// The bias blocks are pure HBM-write (268 MB, ~42 us of bandwidth) and the
// GEMM blocks are MFMA/LDS-bound with low HBM demand — co-resident they
// overlap, hiding the bias write under GEMM compute (single-stream-legal
// heterogeneous fusion).
//
// GEMM: C[4096,3072] = Ah @ Wqt^T, 128x128 tile, BK=32, 4 waves 2x2, 4x4
// mfma_f32_16x16x32_f16 frags/wave; fragment-native LDS + global_load_lds.
// Epilogue scatters fp16 Q,K,V to [b,h,s,d].
// Bias: block bb=0..511 writes rows bb*64..+63 of out[(h*S+q)][k] (h uniform).
// ---------------------------------------------------------------------------
__global__ __launch_bounds__(256) void qkv_bias_kernel(const half_t* __restrict__ A,
                                                       const half_t* __restrict__ Bt,
                                                       half_t* __restrict__ Qo,
                                                       half_t* __restrict__ Ko,
                                                       half_t* __restrict__ Vo,
                                                       const float* __restrict__ table,
                                                       float* __restrict__ bias_out) {
  __shared__ half_t Asl[8 * 512];
  __shared__ half_t Bsl[8 * 512];
  __shared__ float tb[32];

  const int tid = threadIdx.x;

  if (blockIdx.x >= 768) {
    // ---------------- position_bias branch ----------------
    const int bb = blockIdx.x - 768;        // 0..511
    const int row0 = bb * 64;               // 64 rows, h uniform (2048 rows/h)
    const int h = row0 >> 11;
    if (tid < 32) tb[tid] = table[tid * NH + h];
    __syncthreads();
    const int k0 = tid * 4;
    for (int rr = 0; rr < 64; rr++) {
      const int row = row0 + rr;
      const int q = row & (S_LEN - 1);
      float* dst = bias_out + (size_t)row * S_LEN;
#pragma unroll
      for (int half = 0; half < 2; half++) {
        int k = k0 + half * 1024;
        float4 v;
        v.x = tb[t5_bucket((k + 0) - q)];
        v.y = tb[t5_bucket((k + 1) - q)];
        v.z = tb[t5_bucket((k + 2) - q)];
        v.w = tb[t5_bucket((k + 3) - q)];
        *(float4*)(dst + k) = v;
      }
    }
    return;
  }

  // ---------------- QKV GEMM branch ----------------
  const int K = 1024, N = 3072;
  const int w = tid >> 6;
  const int lane = tid & 63;
  const int l15 = lane & 15;
  const int quad = lane >> 4;
  const int wm = w >> 1, wn = w & 1;
  const int m0 = (blockIdx.x / 24) * 128;
  const int n0 = (blockIdx.x % 24) * 128;

  floatx4 acc[4][4];
#pragma unroll
  for (int i = 0; i < 4; i++)
#pragma unroll
    for (int j = 0; j < 4; j++) acc[i][j] = (floatx4){0.f, 0.f, 0.f, 0.f};

  const half_t* ga0 = A + (size_t)(m0 + (2 * w + 0) * 16 + l15) * K + quad * 8;
  const half_t* ga1 = A + (size_t)(m0 + (2 * w + 1) * 16 + l15) * K + quad * 8;
  const half_t* gb0 = Bt + (size_t)(n0 + (2 * w + 0) * 16 + l15) * K + quad * 8;
  const half_t* gb1 = Bt + (size_t)(n0 + (2 * w + 1) * 16 + l15) * K + quad * 8;
  half_t* la0 = &Asl[(2 * w + 0) * 512];
  half_t* la1 = &Asl[(2 * w + 1) * 512];
  half_t* lb0 = &Bsl[(2 * w + 0) * 512];
  half_t* lb1 = &Bsl[(2 * w + 1) * 512];

  for (int k0 = 0; k0 < K; k0 += 32) {
    __syncthreads();
    load_lds16(ga0 + k0, la0);
    load_lds16(ga1 + k0, la1);
    load_lds16(gb0 + k0, lb0);
    load_lds16(gb1 + k0, lb1);
    __syncthreads();

    half8 af[4], bf[4];
#pragma unroll
    for (int i = 0; i < 4; i++) af[i] = *(half8*)&Asl[(wm * 4 + i) * 512 + lane * 8];
#pragma unroll
    for (int j = 0; j < 4; j++) bf[j] = *(half8*)&Bsl[(wn * 4 + j) * 512 + lane * 8];
#pragma unroll
    for (int i = 0; i < 4; i++)
#pragma unroll
      for (int j = 0; j < 4; j++)
        acc[i][j] = __builtin_amdgcn_mfma_f32_16x16x32_f16(af[i], bf[j], acc[i][j], 0, 0, 0);
  }

  const int rowbase = m0 + wm * 64;
  const int colbase = n0 + wn * 64;
  const int which = colbase >> 10;            // 0=q,1=k,2=v (uniform per wave)
  const int h = (colbase & 1023) >> 6;        // uniform per wave
  const int b = rowbase >> 11;
  const int s0 = rowbase & (S_LEN - 1);
  half_t* base = ((which == 0) ? Qo : (which == 1) ? Ko : Vo) +
                 (size_t)(b * NH + h) * S_LEN * DKV;
#pragma unroll
  for (int i = 0; i < 4; i++)
#pragma unroll
    for (int j = 0; j < 4; j++)
#pragma unroll
      for (int r = 0; r < 4; r++)
        base[(size_t)(s0 + i * 16 + quad * 4 + r) * DKV + j * 16 + l15] =
            (half_t)acc[i][j][r];
}

// ---------------------------------------------------------------------------
// Output-projection fp16 MFMA GEMM: C[4096,1024] = Xh @ Wot^T -> fp32 d_out.
// Same m97-validated structure (BK=32, 16 KB LDS, no min-wave clamp).
// ---------------------------------------------------------------------------
__global__ __launch_bounds__(256) void hgemm_out(const half_t* __restrict__ A,
                                                 const half_t* __restrict__ Bt,
                                                 float* __restrict__ C) {
  __shared__ half_t Asl[8 * 512];
  __shared__ half_t Bsl[8 * 512];

  const int K = 1024, N = 1024;
  const int tid = threadIdx.x;
  const int w = tid >> 6;
  const int lane = tid & 63;
  const int l15 = lane & 15;
  const int quad = lane >> 4;
  const int wm = w >> 1, wn = w & 1;
  const int m0 = blockIdx.y * 128;
  const int n0 = blockIdx.x * 128;

  floatx4 acc[4][4];
#pragma unroll
  for (int i = 0; i < 4; i++)
#pragma unroll
    for (int j = 0; j < 4; j++) acc[i][j] = (floatx4){0.f, 0.f, 0.f, 0.f};

  const half_t* ga0 = A + (size_t)(m0 + (2 * w + 0) * 16 + l15) * K + quad * 8;
  const half_t* ga1 = A + (size_t)(m0 + (2 * w + 1) * 16 + l15) * K + quad * 8;
  const half_t* gb0 = Bt + (size_t)(n0 + (2 * w + 0) * 16 + l15) * K + quad * 8;
  const half_t* gb1 = Bt + (size_t)(n0 + (2 * w + 1) * 16 + l15) * K + quad * 8;
  half_t* la0 = &Asl[(2 * w + 0) * 512];
  half_t* la1 = &Asl[(2 * w + 1) * 512];
  half_t* lb0 = &Bsl[(2 * w + 0) * 512];
  half_t* lb1 = &Bsl[(2 * w + 1) * 512];

  for (int k0 = 0; k0 < K; k0 += 32) {
    __syncthreads();
    load_lds16(ga0 + k0, la0);
    load_lds16(ga1 + k0, la1);
    load_lds16(gb0 + k0, lb0);
    load_lds16(gb1 + k0, lb1);
    __syncthreads();

    half8 af[4], bf[4];
#pragma unroll
    for (int i = 0; i < 4; i++) af[i] = *(half8*)&Asl[(wm * 4 + i) * 512 + lane * 8];
#pragma unroll
    for (int j = 0; j < 4; j++) bf[j] = *(half8*)&Bsl[(wn * 4 + j) * 512 + lane * 8];
#pragma unroll
    for (int i = 0; i < 4; i++)
#pragma unroll
      for (int j = 0; j < 4; j++)
        acc[i][j] = __builtin_amdgcn_mfma_f32_16x16x32_f16(af[i], bf[j], acc[i][j], 0, 0, 0);
  }

  const int rowbase = m0 + wm * 64;
  const int colbase = n0 + wn * 64;
#pragma unroll
  for (int i = 0; i < 4; i++)
#pragma unroll
    for (int j = 0; j < 4; j++)
#pragma unroll
      for (int r = 0; r < 4; r++)
        C[(size_t)(rowbase + i * 16 + quad * 4 + r) * N + colbase + j * 16 + l15] =
            acc[i][j][r];
}

// ---------------------------------------------------------------------------
// fp16 MFMA flash attention, SPLIT-K over keys (2 partitions of 1024).
// Unchanged from round 7 (softmax folded into MFMA; additive bias table;
// ds_swizzle max; no min-wave clamp).
// ---------------------------------------------------------------------------
__global__ __launch_bounds__(256) void attn_split(const half_t* __restrict__ Q,
                                                  const half_t* __restrict__ K,
                                                  const half_t* __restrict__ Vt,
                                                  const float* __restrict__ table,
                                                  float* __restrict__ Opart,
                                                  float* __restrict__ Mp,
                                                  float* __restrict__ Lp) {
  __shared__ half_t Ks[64 * 64];    // [key][d] swizzled
  __shared__ half_t Vts[64 * 64];   // [d][key] swizzled
  __shared__ half_t Ps[64 * 68];    // [q][key], stride 68
  __shared__ float tb[32];
  __shared__ float badd[184];       // bias by clamp(delta,-91,91)+91

  const int tid = threadIdx.x;
  const int w = tid >> 6;
  const int lane = tid & 63;
  const int l15 = lane & 15;
  const int quad = lane >> 4;
  const int bh = blockIdx.y;
  const int h = bh & (NH - 1);
  const int part = blockIdx.x & 1;
  const int q0w = (blockIdx.x >> 1) * 64 + w * 16;

  if (tid < 32) tb[tid] = table[tid * NH + h];
  __syncthreads();
  if (tid < 183) badd[tid] = tb[t5_bucket(tid - 91)];
  const float tb_neg = tb[15], tb_pos = tb[31];   // capped-region biases

  half8 qf[2];
#pragma unroll
  for (int ks = 0; ks < 2; ks++)
    qf[ks] = *(const half8*)(Q + ((size_t)bh * S_LEN + q0w + l15) * DKV +
                             ks * 32 + quad * 8);

  // ones-column B fragment: B[k][0]=1, B[k][n>0]=0
  half8 bones;
#pragma unroll
  for (int j = 0; j < 8; j++) bones[j] = (l15 == 0) ? (half_t)1.0f : (half_t)0.0f;

  floatx4 o[4], oL;
  float m[4];
#pragma unroll
  for (int r = 0; r < 4; r++) m[r] = -1e30f;
#pragma unroll
  for (int nb = 0; nb < 4; nb++) o[nb] = (floatx4){0.f, 0.f, 0.f, 0.f};
  oL = (floatx4){0.f, 0.f, 0.f, 0.f};

  const int jr = tid >> 2;
  const int ub = (tid & 3) * 2;
  const int sw = jr & 7;
  const int kv_rd0 = l15 * 64 + ((0 * 4 + quad) ^ (l15 & 7)) * 8;   // ks=0
  const int kv_rd1 = l15 * 64 + ((1 * 4 + quad) ^ (l15 & 7)) * 8;   // ks=1
  const int ps_wr = (w * 16 + quad * 4) * 68 + l15;
  const int ps_rd = (w * 16 + l15) * 68 + quad * 8;

  const half_t* Kg = K + ((size_t)bh * S_LEN + part * 1024 + jr) * DKV + ub * 8;
  const half_t* Vg = Vt + ((size_t)bh * DKV + jr) * S_LEN + part * 1024 + ub * 8;
  int rel = part * 1024 - q0w;   // kc - q0w, wave-uniform

  for (int it = 0; it < 16; it++, rel += 64, Kg += 64 * DKV, Vg += 64) {
    __syncthreads();
    {
      half8 k0v = *(const half8*)(Kg);
      half8 k1v = *(const half8*)(Kg + 8);
      half8 v0v = *(const half8*)(Vg);
      half8 v1v = *(const half8*)(Vg + 8);
      *(half8*)&Ks[jr * 64 + ((ub + 0) ^ sw) * 8] = k0v;
      *(half8*)&Ks[jr * 64 + ((ub + 1) ^ sw) * 8] = k1v;
      *(half8*)&Vts[jr * 64 + ((ub + 0) ^ sw) * 8] = v0v;
      *(half8*)&Vts[jr * 64 + ((ub + 1) ^ sw) * 8] = v1v;
    }
    __syncthreads();

    // ---- S = Q K^T ----
    floatx4 s[4];
#pragma unroll
    for (int nb = 0; nb < 4; nb++) {
      s[nb] = (floatx4){0.f, 0.f, 0.f, 0.f};
      s[nb] = __builtin_amdgcn_mfma_f32_16x16x32_f16(
          qf[0], *(half8*)&Ks[nb * 1024 + kv_rd0], s[nb], 0, 0, 0);
      s[nb] = __builtin_amdgcn_mfma_f32_16x16x32_f16(
          qf[1], *(half8*)&Ks[nb * 1024 + kv_rd1], s[nb], 0, 0, 0);
    }

    // ---- online softmax ----
    float al[4];
    if (rel >= 106 || rel <= -154) {
      const float lb = (rel >= 106) ? tb_pos : tb_neg;   // uniform capped bias
#pragma unroll
      for (int r = 0; r < 4; r++) {
        float cm = qmax16(fmaxf(fmaxf(s[0][r], s[1][r]), fmaxf(s[2][r], s[3][r])));
        float mn = fmaxf(m[r], cm);
        al[r] = __expf(m[r] - mn);
        m[r] = mn;
        float sh = lb - mn;
#pragma unroll
        for (int nb = 0; nb < 4; nb++)
          Ps[ps_wr + r * 68 + nb * 16] = (half_t)__expf(s[nb][r] + sh);
#pragma unroll
        for (int nb = 0; nb < 4; nb++) o[nb][r] *= al[r];
        oL[r] *= al[r];
      }
    } else {
#pragma unroll
      for (int r = 0; r < 4; r++) {
        int db = rel + l15 - (quad * 4 + r) + 91;   // delta+91 at nb=0
        float bv[4];
#pragma unroll
        for (int nb = 0; nb < 4; nb++) {
          int idx = db + nb * 16;
          idx = idx < 0 ? 0 : (idx > 182 ? 182 : idx);
          bv[nb] = badd[idx];
        }
        float cm = qmax16(fmaxf(fmaxf(s[0][r], s[1][r]), fmaxf(s[2][r], s[3][r])));
        float mn = fmaxf(m[r], cm);
        al[r] = __expf(m[r] - mn);
        m[r] = mn;
#pragma unroll
        for (int nb = 0; nb < 4; nb++)
          Ps[ps_wr + r * 68 + nb * 16] = (half_t)__expf(s[nb][r] - mn + bv[nb]);
#pragma unroll
        for (int nb = 0; nb < 4; nb++) o[nb][r] *= al[r];
        oL[r] *= al[r];
      }
    }

    // ---- O += P V ; l += P . ones ----
    half8 af0 = *(half8*)&Ps[ps_rd];
    half8 af1 = *(half8*)&Ps[ps_rd + 32];
#pragma unroll
    for (int nb = 0; nb < 4; nb++) {
      o[nb] = __builtin_amdgcn_mfma_f32_16x16x32_f16(
          af0, *(half8*)&Vts[nb * 1024 + kv_rd0], o[nb], 0, 0, 0);
      o[nb] = __builtin_amdgcn_mfma_f32_16x16x32_f16(
          af1, *(half8*)&Vts[nb * 1024 + kv_rd1], o[nb], 0, 0, 0);
    }
    oL = __builtin_amdgcn_mfma_f32_16x16x32_f16(af0, bones, oL, 0, 0, 0);
    oL = __builtin_amdgcn_mfma_f32_16x16x32_f16(af1, bones, oL, 0, 0, 0);
  }

  // ---- epilogue: unnormalized partials; l lives in oL at col l15==0 ----
#pragma unroll
  for (int r = 0; r < 4; r++) {
    int row = bh * S_LEN + q0w + quad * 4 + r;   // bh*2048 + q
    float* op = Opart + (size_t)part * 4194304 + (size_t)row * 64;
#pragma unroll
    for (int nb = 0; nb < 4; nb++) op[nb * 16 + l15] = o[nb][r];
    if (l15 == 0) {
      Mp[part * 65536 + row] = m[r];
      Lp[part * 65536 + row] = oL[r];
    }
  }
}

// ---------------------------------------------------------------------------
// Merge the 2 split-K partials: exact flash-decode combine, write X fp16.
// ---------------------------------------------------------------------------
__global__ __launch_bounds__(256) void attn_combine(const float* __restrict__ Opart,
                                                    const float* __restrict__ Mp,
                                                    const float* __restrict__ Lp,
                                                    half_t* __restrict__ X) {
  int idx = blockIdx.x * 256 + threadIdx.x;
  int row = idx >> 6;        // bh*2048 + q
  int d = idx & 63;
  float m0 = Mp[row], m1 = Mp[65536 + row];
  float l0 = Lp[row], l1 = Lp[65536 + row];
  float M = fmaxf(m0, m1);
  float a0 = __expf(m0 - M), a1 = __expf(m1 - M);
  float L = l0 * a0 + l1 * a1;
  float o = (Opart[(size_t)row * 64 + d] * a0 +
             Opart[4194304 + (size_t)row * 64 + d] * a1) / L;
  int bh = row >> 11, q = row & (S_LEN - 1);
  int b = bh >> 4, h = bh & (NH - 1);
  X[(size_t)(b * S_LEN + q) * DMODEL + h * DKV + d] = (half_t)o;
}

// ---------------------------------------------------------------------------
// kernel_launch
// ws layout (halves): Ah 4M (reused as Vt) | Wqt 3M | Wot 1M | Qh 4M | Kh 4M |
//   Vh 4M | Xh 4M | then f32: Opart 8.39M | Mp 131072 | Lp 131072  (~90 MB)
// ---------------------------------------------------------------------------
extern "C" void kernel_launch(void* const* d_in, const int* in_sizes, int n_in,
                              void* d_out, int out_size, void* d_ws, size_t ws_size,
                              hipStream_t stream) {
  const float* hidden = (const float*)d_in[0];
  const float* w_qkv = (const float*)d_in[1];
  const float* w_o = (const float*)d_in[2];
  const float* table = (const float*)d_in[3];

  float* attn_out = (float*)d_out;
  float* bias_out = (float*)d_out + 4194304;

  half_t* Ah  = (half_t*)d_ws;     // hidden fp16; reused as Vt after QKV GEMM
  half_t* Wqt = Ah + 4194304;      // [3072][1024]
  half_t* Wot = Wqt + 3145728;     // [1024][1024]
  half_t* Qh  = Wot + 1048576;     // [b,h,s,d]
  half_t* Kh  = Qh + 4194304;      // [b,h,s,d]
  half_t* Vh  = Kh + 4194304;      // [b,h,s,d]
  half_t* Xh  = Vh + 4194304;      // [4096][1024]
  half_t* Vth = Ah;                // [b,h,d,s] (aliases Ah; Ah dead by then)
  float* Opart = (float*)(Xh + 4194304);   // 2 x 4,194,304 f32
  float* Mpp   = Opart + 8388608;          // 2 x 65536
  float* Lpp   = Mpp + 131072;             // 2 x 65536

  // 1) fused prep: hidden cast + both weight transposes
  prep_kernel<<<8192, 256, 0, stream>>>(hidden, w_qkv, w_o, Ah, Wqt, Wot);

  // 2) FUSED QKV GEMM (768 blocks) + position_bias write (512 blocks):
  //    bias HBM writes overlap GEMM compute within one dispatch
  qkv_bias_kernel<<<768 + 512, 256, 0, stream>>>(Ah, Wqt, Qh, Kh, Vh, table, bias_out);

  // 3) V -> Vt transpose (Ah is dead now; Vt aliases it)
  vtrans<<<dim3(S_LEN / 64, BATCH * NH), 256, 0, stream>>>(Vh, Vth);

  // 4) split-K fp16 MFMA flash attention -> partials, then combine -> Xh
  attn_split<<<dim3((S_LEN / 64) * 2, BATCH * NH), 256, 0, stream>>>(
      Qh, Kh, Vth, table, Opart, Mpp, Lpp);
  attn_combine<<<4194304 / 256, 256, 0, stream>>>(Opart, Mpp, Lpp, Xh);

  // 5) output projection -> d_out fp32
  hgemm_out<<<dim3(1024 / 128, 4096 / 128), 256, 0, stream>>>(Xh, Wot, attn_out);
}

// Round 9
// 512.927 us; speedup vs baseline: 1.0665x; 1.0665x over previous
//
#include <hip/hip_runtime.h>
#include <hip/hip_bf16.h>
#include <cstdint>
#include <cstddef>

// Problem constants (T5 self-attention, B=2, S=2048, H=16, D=64, d_model=1024)
#define S_LEN 2048
#define NH 16
#define DKV 64
#define BATCH 2
#define DMODEL 1024
#define LOG2E 1.4426950408889634f

typedef _Float16 half_t;
typedef __attribute__((ext_vector_type(4))) _Float16 halfx4;  // 8 B
typedef __attribute__((ext_vector_type(8))) _Float16 half8;   // MFMA A/B frag (4 VGPRs)
typedef __attribute__((ext_vector_type(4))) float floatx4;    // MFMA C/D frag

// async global->LDS, 16 B per lane; LDS dest = wave-uniform base + lane*16
__device__ __forceinline__ void load_lds16(const half_t* g, half_t* l) {
  __builtin_amdgcn_global_load_lds((const __attribute__((address_space(1))) void*)g,
                                   (__attribute__((address_space(3))) void*)l, 16, 0, 0);
}

// max-reduce over 16 lanes (l15 within quad) via ds_swizzle xor 1,2,4,8
__device__ __forceinline__ float qmax16(float v) {
  int i;
  i = __builtin_amdgcn_ds_swizzle(__float_as_int(v), 0x041F); v = fmaxf(v, __int_as_float(i));
  i = __builtin_amdgcn_ds_swizzle(__float_as_int(v), 0x081F); v = fmaxf(v, __int_as_float(i));
  i = __builtin_amdgcn_ds_swizzle(__float_as_int(v), 0x101F); v = fmaxf(v, __int_as_float(i));
  i = __builtin_amdgcn_ds_swizzle(__float_as_int(v), 0x201F); v = fmaxf(v, __int_as_float(i));
  return v;
}

// ---------------------------------------------------------------------------
// T5 relative-position bucket — EXACT integer thresholds (ceil(8*16^(n/8))),
// verified to agree with the fp32 reference at every integer delta.
// Capped for |delta| >= 91 -> 183-entry table covers all deltas.
// ---------------------------------------------------------------------------
__device__ __forceinline__ int t5_bucket(int delta) {
  int base = (delta > 0) ? 16 : 0;
  int a = delta < 0 ? -delta : delta;
  int n;
  if (a < 8)       n = a;
  else if (a < 12) n = 8;
  else if (a < 16) n = 9;
  else if (a < 23) n = 10;
  else if (a < 32) n = 11;
  else if (a < 46) n = 12;
  else if (a < 64) n = 13;
  else if (a < 91) n = 14;
  else             n = 15;
  return base + n;
}

// ---------------------------------------------------------------------------
// position_bias output: out[(h*S + q)*S + k] = table[bucket(k-q)*NH + h]
// Memory-bound 268 MB write. One row per block (32768 blocks) — the fused
// 64-rows-per-block variant (round 8) serialized as a dispatch tail and
// regressed; this shape saturates write BW.
// ---------------------------------------------------------------------------
__global__ __launch_bounds__(256) void bias_kernel(const float* __restrict__ table,
                                                   float* __restrict__ out) {
  int h = blockIdx.x >> 11;
  int q = blockIdx.x & (S_LEN - 1);
  __shared__ float tb[32];
  if (threadIdx.x < 32) tb[threadIdx.x] = table[threadIdx.x * NH + h];
  __syncthreads();
  float* dst = out + (size_t)blockIdx.x * S_LEN;
  int k0 = threadIdx.x * 4;
#pragma unroll
  for (int half = 0; half < 2; half++) {
    int k = k0 + half * 1024;
    float4 v;
    v.x = tb[t5_bucket((k + 0) - q)];
    v.y = tb[t5_bucket((k + 1) - q)];
    v.z = tb[t5_bucket((k + 2) - q)];
    v.w = tb[t5_bucket((k + 3) - q)];
    *(float4*)(dst + k) = v;
  }
}

// ---------------------------------------------------------------------------
// Fused prep: fp32->fp16 cast of hidden (blocks 0..4095), w_qkv transpose-cast
// (blocks 4096..7167), w_o transpose-cast (blocks 7168..8191).
// ---------------------------------------------------------------------------
__global__ __launch_bounds__(256) void prep_kernel(const float* __restrict__ hidden,
                                                   const float* __restrict__ w_qkv,
                                                   const float* __restrict__ w_o,
                                                   half_t* __restrict__ Ah,
                                                   half_t* __restrict__ Wqt,
                                                   half_t* __restrict__ Wot) {
  __shared__ float t[32][33];
  const int bx = blockIdx.x;
  if (bx < 4096) {
    int i = bx * 256 + threadIdx.x;
    float4 v = ((const float4*)hidden)[i];
    halfx4 h;
    h[0] = (half_t)v.x; h[1] = (half_t)v.y; h[2] = (half_t)v.z; h[3] = (half_t)v.w;
    ((halfx4*)Ah)[i] = h;
    return;
  }
  const float* in;
  half_t* out;
  int R, C, bb;
  if (bx < 4096 + 3072) {
    bb = bx - 4096; in = w_qkv; out = Wqt; R = 1024; C = 3072;
  } else {
    bb = bx - 7168; in = w_o; out = Wot; R = 1024; C = 1024;
  }
  const int ct = C / 32;
  const int c0 = (bb % ct) * 32, r0 = (bb / ct) * 32;
  const int lr = threadIdx.x >> 3;
  const int lc = (threadIdx.x & 7) * 4;
  float4 v = *(const float4*)(in + (size_t)(r0 + lr) * C + c0 + lc);
  t[lr][lc + 0] = v.x; t[lr][lc + 1] = v.y; t[lr][lc + 2] = v.z; t[lr][lc + 3] = v.w;
  __syncthreads();
  halfx4 hv;
#pragma unroll
  for (int u = 0; u < 4; u++) hv[u] = (half_t)t[lc + u][lr];
  *(halfx4*)(out + (size_t)(c0 + lr) * R + r0 + lc) = hv;
}

// ---------------------------------------------------------------------------
// fp16 [b,h,s,d] -> [b,h,d,s] transpose (V). 64x64 tile per block.
// ---------------------------------------------------------------------------
__global__ __launch_bounds__(256) void vtrans(const half_t* __restrict__ V,
                                              half_t* __restrict__ Vt) {
  __shared__ half_t T[64 * 72];
  const int bh = blockIdx.y;
  const int s0 = blockIdx.x * 64;
  const half_t* src = V + ((size_t)bh * S_LEN + s0) * DKV;
  half_t* dst = Vt + (size_t)bh * DKV * S_LEN + s0;
  const int sr = threadIdx.x >> 3;        // 0..31
  const int dc = (threadIdx.x & 7) * 8;   // 0..56
#pragma unroll
  for (int p = 0; p < 2; p++) {
    int s = sr + p * 32;
    half8 v = *(const half8*)(src + (size_t)s * DKV + dc);
#pragma unroll
    for (int u = 0; u < 8; u++) T[(dc + u) * 72 + s] = v[u];
  }
  __syncthreads();
#pragma unroll
  for (int p = 0; p < 2; p++) {
    int d = sr + p * 32;
    half8 v = *(half8*)&T[d * 72 + dc];
    *(half8*)(dst + (size_t)d * S_LEN + dc) = v;
  }
}

// ---------------------------------------------------------------------------
// fp16 MFMA GEMM: C[M,N] = A[M,K] @ Bt[N,K]^T. 128x128 tile, BK=32, 256 thr
// (4 waves, 2x2), 4x4 mfma_f32_16x16x32_f16 frags per wave (m97 structure).
// MODE 0: fp32 store to C.
// MODE 1: QKV scatter epilogue -> fp16 [b,h,s,d]; Q is PRE-SCALED by log2(e)
//         so the attention softmax can use raw v_exp_f32 (2^x) directly.
// ---------------------------------------------------------------------------
template <int MODE>
__global__ __launch_bounds__(256) void hgemm128(const half_t* __restrict__ A,
                                                const half_t* __restrict__ Bt,
                                                float* __restrict__ C,
                                                half_t* __restrict__ Qo,
                                                half_t* __restrict__ Ko,
                                                half_t* __restrict__ Vo,
                                                int M, int N, int K) {
  __shared__ half_t Asl[8 * 512];
  __shared__ half_t Bsl[8 * 512];

  const int tid = threadIdx.x;
  const int w = tid >> 6;
  const int lane = tid & 63;
  const int l15 = lane & 15;
  const int quad = lane >> 4;
  const int wm = w >> 1, wn = w & 1;
  const int m0 = blockIdx.y * 128;
  const int n0 = blockIdx.x * 128;

  floatx4 acc[4][4];
#pragma unroll
  for (int i = 0; i < 4; i++)
#pragma unroll
    for (int j = 0; j < 4; j++) acc[i][j] = (floatx4){0.f, 0.f, 0.f, 0.f};

  const half_t* ga0 = A + (size_t)(m0 + (2 * w + 0) * 16 + l15) * K + quad * 8;
  const half_t* ga1 = A + (size_t)(m0 + (2 * w + 1) * 16 + l15) * K + quad * 8;
  const half_t* gb0 = Bt + (size_t)(n0 + (2 * w + 0) * 16 + l15) * K + quad * 8;
  const half_t* gb1 = Bt + (size_t)(n0 + (2 * w + 1) * 16 + l15) * K + quad * 8;
  half_t* la0 = &Asl[(2 * w + 0) * 512];
  half_t* la1 = &Asl[(2 * w + 1) * 512];
  half_t* lb0 = &Bsl[(2 * w + 0) * 512];
  half_t* lb1 = &Bsl[(2 * w + 1) * 512];

  for (int k0 = 0; k0 < K; k0 += 32) {
    __syncthreads();
    load_lds16(ga0 + k0, la0);
    load_lds16(ga1 + k0, la1);
    load_lds16(gb0 + k0, lb0);
    load_lds16(gb1 + k0, lb1);
    __syncthreads();

    half8 af[4], bf[4];
#pragma unroll
    for (int i = 0; i < 4; i++) af[i] = *(half8*)&Asl[(wm * 4 + i) * 512 + lane * 8];
#pragma unroll
    for (int j = 0; j < 4; j++) bf[j] = *(half8*)&Bsl[(wn * 4 + j) * 512 + lane * 8];
#pragma unroll
    for (int i = 0; i < 4; i++)
#pragma unroll
      for (int j = 0; j < 4; j++)
        acc[i][j] = __builtin_amdgcn_mfma_f32_16x16x32_f16(af[i], bf[j], acc[i][j], 0, 0, 0);
  }

  const int rowbase = m0 + wm * 64;
  const int colbase = n0 + wn * 64;
  if (MODE == 0) {
#pragma unroll
    for (int i = 0; i < 4; i++)
#pragma unroll
      for (int j = 0; j < 4; j++)
#pragma unroll
        for (int r = 0; r < 4; r++)
          C[(size_t)(rowbase + i * 16 + quad * 4 + r) * N + colbase + j * 16 + l15] =
              acc[i][j][r];
  } else {
    const int which = colbase >> 10;            // 0=q,1=k,2=v (uniform per wave)
    const int h = (colbase & 1023) >> 6;        // uniform per wave
    const int b = rowbase >> 11;
    const int s0 = rowbase & (S_LEN - 1);
    const float scale = (which == 0) ? LOG2E : 1.0f;   // Q pre-scaled for exp2
    half_t* base = ((which == 0) ? Qo : (which == 1) ? Ko : Vo) +
                   (size_t)(b * NH + h) * S_LEN * DKV;
#pragma unroll
    for (int i = 0; i < 4; i++)
#pragma unroll
      for (int j = 0; j < 4; j++)
#pragma unroll
        for (int r = 0; r < 4; r++)
          base[(size_t)(s0 + i * 16 + quad * 4 + r) * DKV + j * 16 + l15] =
              (half_t)(acc[i][j][r] * scale);
  }
}

// ---------------------------------------------------------------------------
// fp16 MFMA flash attention, SPLIT-K over keys (2 partitions of 1024).
// EXP2 DOMAIN: Q is pre-scaled by log2(e), bias table pre-multiplied by
// log2(e) -> every per-element exp is a bare exp2f (saves the v_mul that
// __expf folds in, ~134M of them). m/l bookkeeping is in the log2 domain.
// Softmax denominator folded into MFMA (ones-column B frag -> oL); ds_swizzle
// max; no min-wave clamp.
// ---------------------------------------------------------------------------
__global__ __launch_bounds__(256) void attn_split(const half_t* __restrict__ Q,
                                                  const half_t* __restrict__ K,
                                                  const half_t* __restrict__ Vt,
                                                  const float* __restrict__ table,
                                                  float* __restrict__ Opart,
                                                  float* __restrict__ Mp,
                                                  float* __restrict__ Lp) {
  __shared__ half_t Ks[64 * 64];    // [key][d] swizzled
  __shared__ half_t Vts[64 * 64];   // [d][key] swizzled
  __shared__ half_t Ps[64 * 68];    // [q][key], stride 68
  __shared__ float tb[32];
  __shared__ float badd[184];       // log2e * bias by clamp(delta,-91,91)+91

  const int tid = threadIdx.x;
  const int w = tid >> 6;
  const int lane = tid & 63;
  const int l15 = lane & 15;
  const int quad = lane >> 4;
  const int bh = blockIdx.y;
  const int h = bh & (NH - 1);
  const int part = blockIdx.x & 1;
  const int q0w = (blockIdx.x >> 1) * 64 + w * 16;

  if (tid < 32) tb[tid] = table[tid * NH + h] * LOG2E;
  __syncthreads();
  if (tid < 183) badd[tid] = tb[t5_bucket(tid - 91)];
  const float tb_neg = tb[15], tb_pos = tb[31];   // capped-region biases (scaled)

  half8 qf[2];
#pragma unroll
  for (int ks = 0; ks < 2; ks++)
    qf[ks] = *(const half8*)(Q + ((size_t)bh * S_LEN + q0w + l15) * DKV +
                             ks * 32 + quad * 8);

  // ones-column B fragment: B[k][0]=1, B[k][n>0]=0
  half8 bones;
#pragma unroll
  for (int j = 0; j < 8; j++) bones[j] = (l15 == 0) ? (half_t)1.0f : (half_t)0.0f;

  floatx4 o[4], oL;
  float m[4];
#pragma unroll
  for (int r = 0; r < 4; r++) m[r] = -1e30f;
#pragma unroll
  for (int nb = 0; nb < 4; nb++) o[nb] = (floatx4){0.f, 0.f, 0.f, 0.f};
  oL = (floatx4){0.f, 0.f, 0.f, 0.f};

  const int jr = tid >> 2;
  const int ub = (tid & 3) * 2;
  const int sw = jr & 7;
  const int kv_rd0 = l15 * 64 + ((0 * 4 + quad) ^ (l15 & 7)) * 8;   // ks=0
  const int kv_rd1 = l15 * 64 + ((1 * 4 + quad) ^ (l15 & 7)) * 8;   // ks=1
  const int ps_wr = (w * 16 + quad * 4) * 68 + l15;
  const int ps_rd = (w * 16 + l15) * 68 + quad * 8;

  const half_t* Kg = K + ((size_t)bh * S_LEN + part * 1024 + jr) * DKV + ub * 8;
  const half_t* Vg = Vt + ((size_t)bh * DKV + jr) * S_LEN + part * 1024 + ub * 8;
  int rel = part * 1024 - q0w;   // kc - q0w, wave-uniform

  for (int it = 0; it < 16; it++, rel += 64, Kg += 64 * DKV, Vg += 64) {
    __syncthreads();
    {
      half8 k0v = *(const half8*)(Kg);
      half8 k1v = *(const half8*)(Kg + 8);
      half8 v0v = *(const half8*)(Vg);
      half8 v1v = *(const half8*)(Vg + 8);
      *(half8*)&Ks[jr * 64 + ((ub + 0) ^ sw) * 8] = k0v;
      *(half8*)&Ks[jr * 64 + ((ub + 1) ^ sw) * 8] = k1v;
      *(half8*)&Vts[jr * 64 + ((ub + 0) ^ sw) * 8] = v0v;
      *(half8*)&Vts[jr * 64 + ((ub + 1) ^ sw) * 8] = v1v;
    }
    __syncthreads();

    // ---- S' = (log2e * Q) K^T ----
    floatx4 s[4];
#pragma unroll
    for (int nb = 0; nb < 4; nb++) {
      s[nb] = (floatx4){0.f, 0.f, 0.f, 0.f};
      s[nb] = __builtin_amdgcn_mfma_f32_16x16x32_f16(
          qf[0], *(half8*)&Ks[nb * 1024 + kv_rd0], s[nb], 0, 0, 0);
      s[nb] = __builtin_amdgcn_mfma_f32_16x16x32_f16(
          qf[1], *(half8*)&Ks[nb * 1024 + kv_rd1], s[nb], 0, 0, 0);
    }

    // ---- online softmax (log2 domain: p = 2^(s' + b' - m')) ----
    float al[4];
    if (rel >= 106 || rel <= -154) {
      const float lb = (rel >= 106) ? tb_pos : tb_neg;   // uniform capped bias
#pragma unroll
      for (int r = 0; r < 4; r++) {
        float cm = qmax16(fmaxf(fmaxf(s[0][r], s[1][r]), fmaxf(s[2][r], s[3][r])));
        float mn = fmaxf(m[r], cm);
        al[r] = exp2f(m[r] - mn);
        m[r] = mn;
        float sh = lb - mn;
#pragma unroll
        for (int nb = 0; nb < 4; nb++)
          Ps[ps_wr + r * 68 + nb * 16] = (half_t)exp2f(s[nb][r] + sh);
#pragma unroll
        for (int nb = 0; nb < 4; nb++) o[nb][r] *= al[r];
        oL[r] *= al[r];
      }
    } else {
#pragma unroll
      for (int r = 0; r < 4; r++) {
        int db = rel + l15 - (quad * 4 + r) + 91;   // delta+91 at nb=0
        float bv[4];
#pragma unroll
        for (int nb = 0; nb < 4; nb++) {
          int idx = db + nb * 16;
          idx = idx < 0 ? 0 : (idx > 182 ? 182 : idx);
          bv[nb] = badd[idx];
        }
        float cm = qmax16(fmaxf(fmaxf(s[0][r], s[1][r]), fmaxf(s[2][r], s[3][r])));
        float mn = fmaxf(m[r], cm);
        al[r] = exp2f(m[r] - mn);
        m[r] = mn;
#pragma unroll
        for (int nb = 0; nb < 4; nb++)
          Ps[ps_wr + r * 68 + nb * 16] = (half_t)exp2f(s[nb][r] - mn + bv[nb]);
#pragma unroll
        for (int nb = 0; nb < 4; nb++) o[nb][r] *= al[r];
        oL[r] *= al[r];
      }
    }

    // ---- O += P V ; l += P . ones ----
    half8 af0 = *(half8*)&Ps[ps_rd];
    half8 af1 = *(half8*)&Ps[ps_rd + 32];
#pragma unroll
    for (int nb = 0; nb < 4; nb++) {
      o[nb] = __builtin_amdgcn_mfma_f32_16x16x32_f16(
          af0, *(half8*)&Vts[nb * 1024 + kv_rd0], o[nb], 0, 0, 0);
      o[nb] = __builtin_amdgcn_mfma_f32_16x16x32_f16(
          af1, *(half8*)&Vts[nb * 1024 + kv_rd1], o[nb], 0, 0, 0);
    }
    oL = __builtin_amdgcn_mfma_f32_16x16x32_f16(af0, bones, oL, 0, 0, 0);
    oL = __builtin_amdgcn_mfma_f32_16x16x32_f16(af1, bones, oL, 0, 0, 0);
  }

  // ---- epilogue: unnormalized partials; l lives in oL at col l15==0 ----
#pragma unroll
  for (int r = 0; r < 4; r++) {
    int row = bh * S_LEN + q0w + quad * 4 + r;   // bh*2048 + q
    float* op = Opart + (size_t)part * 4194304 + (size_t)row * 64;
#pragma unroll
    for (int nb = 0; nb < 4; nb++) op[nb * 16 + l15] = o[nb][r];
    if (l15 == 0) {
      Mp[part * 65536 + row] = m[r];
      Lp[part * 65536 + row] = oL[r];
    }
  }
}

// ---------------------------------------------------------------------------
// Merge the 2 split-K partials (log2-domain m): exact combine, write X fp16.
// ---------------------------------------------------------------------------
__global__ __launch_bounds__(256) void attn_combine(const float* __restrict__ Opart,
                                                    const float* __restrict__ Mp,
                                                    const float* __restrict__ Lp,
                                                    half_t* __restrict__ X) {
  int idx = blockIdx.x * 256 + threadIdx.x;
  int row = idx >> 6;        // bh*2048 + q
  int d = idx & 63;
  float m0 = Mp[row], m1 = Mp[65536 + row];
  float l0 = Lp[row], l1 = Lp[65536 + row];
  float M = fmaxf(m0, m1);
  float a0 = exp2f(m0 - M), a1 = exp2f(m1 - M);
  float L = l0 * a0 + l1 * a1;
  float o = (Opart[(size_t)row * 64 + d] * a0 +
             Opart[4194304 + (size_t)row * 64 + d] * a1) / L;
  int bh = row >> 11, q = row & (S_LEN - 1);
  int b = bh >> 4, h = bh & (NH - 1);
  X[(size_t)(b * S_LEN + q) * DMODEL + h * DKV + d] = (half_t)o;
}

// ---------------------------------------------------------------------------
// kernel_launch
// ws layout (halves): Ah 4M (reused as Vt) | Wqt 3M | Wot 1M | Qh 4M | Kh 4M |
//   Vh 4M | Xh 4M | then f32: Opart 8.39M | Mp 131072 | Lp 131072  (~90 MB)
// ---------------------------------------------------------------------------
extern "C" void kernel_launch(void* const* d_in, const int* in_sizes, int n_in,
                              void* d_out, int out_size, void* d_ws, size_t ws_size,
                              hipStream_t stream) {
  const float* hidden = (const float*)d_in[0];
  const float* w_qkv = (const float*)d_in[1];
  const float* w_o = (const float*)d_in[2];
  const float* table = (const float*)d_in[3];

  float* attn_out = (float*)d_out;
  float* bias_out = (float*)d_out + 4194304;

  half_t* Ah  = (half_t*)d_ws;     // hidden fp16; reused as Vt after QKV GEMM
  half_t* Wqt = Ah + 4194304;      // [3072][1024]
  half_t* Wot = Wqt + 3145728;     // [1024][1024]
  half_t* Qh  = Wot + 1048576;     // [b,h,s,d], pre-scaled by log2e
  half_t* Kh  = Qh + 4194304;      // [b,h,s,d]
  half_t* Vh  = Kh + 4194304;      // [b,h,s,d]
  half_t* Xh  = Vh + 4194304;      // [4096][1024]
  half_t* Vth = Ah;                // [b,h,d,s] (aliases Ah; Ah dead by then)
  float* Opart = (float*)(Xh + 4194304);   // 2 x 4,194,304 f32
  float* Mpp   = Opart + 8388608;          // 2 x 65536
  float* Lpp   = Mpp + 131072;             // 2 x 65536

  // 1) fused prep: hidden cast + both weight transposes
  prep_kernel<<<8192, 256, 0, stream>>>(hidden, w_qkv, w_o, Ah, Wqt, Wot);

  // 2) position_bias (separate, full-grid write parallelism — r8 fusion reverted)
  bias_kernel<<<NH * S_LEN, 256, 0, stream>>>(table, bias_out);

  // 3) QKV projection (fp16 MFMA; Q epilogue pre-scales by log2e)
  hgemm128<1><<<dim3(3072 / 128, 4096 / 128), 256, 0, stream>>>(
      Ah, Wqt, nullptr, Qh, Kh, Vh, 4096, 3072, 1024);

  // 4) V -> Vt transpose (Ah is dead now; Vt aliases it)
  vtrans<<<dim3(S_LEN / 64, BATCH * NH), 256, 0, stream>>>(Vh, Vth);

  // 5) split-K fp16 MFMA flash attention (exp2 domain) -> partials -> Xh
  attn_split<<<dim3((S_LEN / 64) * 2, BATCH * NH), 256, 0, stream>>>(
      Qh, Kh, Vth, table, Opart, Mpp, Lpp);
  attn_combine<<<4194304 / 256, 256, 0, stream>>>(Opart, Mpp, Lpp, Xh);

  // 6) output projection -> d_out fp32
  hgemm128<0><<<dim3(1024 / 128, 4096 / 128), 256, 0, stream>>>(
      Xh, Wot, attn_out, nullptr, nullptr, nullptr, 4096, 1024, 1024);
}

// Round 10
// 497.476 us; speedup vs baseline: 1.0996x; 1.0311x over previous
//
#include <hip/hip_runtime.h>
#include <hip/hip_bf16.h>
#include <cstdint>
#include <cstddef>

// Problem constants (T5 self-attention, B=2, S=2048, H=16, D=64, d_model=1024)
#define S_LEN 2048
#define NH 16
#define DKV 64
#define BATCH 2
#define DMODEL 1024
#define LOG2E 1.4426950408889634f

typedef _Float16 half_t;
typedef __attribute__((ext_vector_type(4))) _Float16 halfx4;  // 8 B (also 16x16x16 A/B frag)
typedef __attribute__((ext_vector_type(8))) _Float16 half8;   // 16x16x32 A/B frag (4 VGPRs)
typedef __attribute__((ext_vector_type(4))) float floatx4;    // MFMA C/D frag

// async global->LDS, 16 B per lane; LDS dest = wave-uniform base + lane*16
__device__ __forceinline__ void load_lds16(const half_t* g, half_t* l) {
  __builtin_amdgcn_global_load_lds((const __attribute__((address_space(1))) void*)g,
                                   (__attribute__((address_space(3))) void*)l, 16, 0, 0);
}

// ---------------------------------------------------------------------------
// T5 relative-position bucket — EXACT integer thresholds (ceil(8*16^(n/8))),
// verified to agree with the fp32 reference at every integer delta.
// Capped for |delta| >= 91 -> 183-entry table covers all deltas.
// ---------------------------------------------------------------------------
__device__ __forceinline__ int t5_bucket(int delta) {
  int base = (delta > 0) ? 16 : 0;
  int a = delta < 0 ? -delta : delta;
  int n;
  if (a < 8)       n = a;
  else if (a < 12) n = 8;
  else if (a < 16) n = 9;
  else if (a < 23) n = 10;
  else if (a < 32) n = 11;
  else if (a < 46) n = 12;
  else if (a < 64) n = 13;
  else if (a < 91) n = 14;
  else             n = 15;
  return base + n;
}

// ---------------------------------------------------------------------------
// position_bias output: out[(h*S + q)*S + k] = table[bucket(k-q)*NH + h]
// Memory-bound 268 MB write; one row per block (write-BW-saturating shape).
// ---------------------------------------------------------------------------
__global__ __launch_bounds__(256) void bias_kernel(const float* __restrict__ table,
                                                   float* __restrict__ out) {
  int h = blockIdx.x >> 11;
  int q = blockIdx.x & (S_LEN - 1);
  __shared__ float tb[32];
  if (threadIdx.x < 32) tb[threadIdx.x] = table[threadIdx.x * NH + h];
  __syncthreads();
  float* dst = out + (size_t)blockIdx.x * S_LEN;
  int k0 = threadIdx.x * 4;
#pragma unroll
  for (int half = 0; half < 2; half++) {
    int k = k0 + half * 1024;
    float4 v;
    v.x = tb[t5_bucket((k + 0) - q)];
    v.y = tb[t5_bucket((k + 1) - q)];
    v.z = tb[t5_bucket((k + 2) - q)];
    v.w = tb[t5_bucket((k + 3) - q)];
    *(float4*)(dst + k) = v;
  }
}

// ---------------------------------------------------------------------------
// fp32 -> fp16 flat cast (hidden_states). (r7's separate prep — the r8/r9
// fused prep is un-A/B'd regression suspect; reverted.)
// ---------------------------------------------------------------------------
__global__ __launch_bounds__(256) void cast_f2h(const float* __restrict__ in,
                                                half_t* __restrict__ out) {
  int i = blockIdx.x * 256 + threadIdx.x;
  float4 v = ((const float4*)in)[i];
  halfx4 h;
  h[0] = (half_t)v.x; h[1] = (half_t)v.y; h[2] = (half_t)v.z; h[3] = (half_t)v.w;
  ((halfx4*)out)[i] = h;
}

// ---------------------------------------------------------------------------
// fp32 [R][C] -> fp16 [C][R] transpose+cast (weights). 32x32 LDS tile.
// ---------------------------------------------------------------------------
__global__ __launch_bounds__(256) void transpose_cast(const float* __restrict__ in,
                                                      half_t* __restrict__ out,
                                                      int R, int C) {
  __shared__ float t[32][33];
  int lr = threadIdx.x >> 3;
  int lc = (threadIdx.x & 7) * 4;
  int r0 = blockIdx.y * 32, c0 = blockIdx.x * 32;
  float4 v = *(const float4*)(in + (size_t)(r0 + lr) * C + c0 + lc);
  t[lr][lc + 0] = v.x; t[lr][lc + 1] = v.y; t[lr][lc + 2] = v.z; t[lr][lc + 3] = v.w;
  __syncthreads();
  halfx4 hv;
#pragma unroll
  for (int u = 0; u < 4; u++) hv[u] = (half_t)t[lc + u][lr];
  *(halfx4*)(out + (size_t)(c0 + lr) * R + r0 + lc) = hv;
}

// ---------------------------------------------------------------------------
// fp16 [b,h,s,d] -> [b,h,d,s] transpose (V). 64x64 tile per block.
// ---------------------------------------------------------------------------
__global__ __launch_bounds__(256) void vtrans(const half_t* __restrict__ V,
                                              half_t* __restrict__ Vt) {
  __shared__ half_t T[64 * 72];
  const int bh = blockIdx.y;
  const int s0 = blockIdx.x * 64;
  const half_t* src = V + ((size_t)bh * S_LEN + s0) * DKV;
  half_t* dst = Vt + (size_t)bh * DKV * S_LEN + s0;
  const int sr = threadIdx.x >> 3;        // 0..31
  const int dc = (threadIdx.x & 7) * 8;   // 0..56
#pragma unroll
  for (int p = 0; p < 2; p++) {
    int s = sr + p * 32;
    half8 v = *(const half8*)(src + (size_t)s * DKV + dc);
#pragma unroll
    for (int u = 0; u < 8; u++) T[(dc + u) * 72 + s] = v[u];
  }
  __syncthreads();
#pragma unroll
  for (int p = 0; p < 2; p++) {
    int d = sr + p * 32;
    half8 v = *(half8*)&T[d * 72 + dc];
    *(half8*)(dst + (size_t)d * S_LEN + dc) = v;
  }
}

// ---------------------------------------------------------------------------
// fp16 MFMA GEMM: C[M,N] = A[M,K] @ Bt[N,K]^T. 128x128 tile, BK=32, 256 thr
// (4 waves, 2x2), 4x4 mfma_f32_16x16x32_f16 frags per wave (m97 structure).
// MODE 0: fp32 store to C.
// MODE 1: QKV scatter epilogue -> fp16 [b,h,s,d]; Q PRE-SCALED by log2(e)
//         so attention softmax uses raw exp2.
// ---------------------------------------------------------------------------
template <int MODE>
__global__ __launch_bounds__(256) void hgemm128(const half_t* __restrict__ A,
                                                const half_t* __restrict__ Bt,
                                                float* __restrict__ C,
                                                half_t* __restrict__ Qo,
                                                half_t* __restrict__ Ko,
                                                half_t* __restrict__ Vo,
                                                int M, int N, int K) {
  __shared__ half_t Asl[8 * 512];
  __shared__ half_t Bsl[8 * 512];

  const int tid = threadIdx.x;
  const int w = tid >> 6;
  const int lane = tid & 63;
  const int l15 = lane & 15;
  const int quad = lane >> 4;
  const int wm = w >> 1, wn = w & 1;
  const int m0 = blockIdx.y * 128;
  const int n0 = blockIdx.x * 128;

  floatx4 acc[4][4];
#pragma unroll
  for (int i = 0; i < 4; i++)
#pragma unroll
    for (int j = 0; j < 4; j++) acc[i][j] = (floatx4){0.f, 0.f, 0.f, 0.f};

  const half_t* ga0 = A + (size_t)(m0 + (2 * w + 0) * 16 + l15) * K + quad * 8;
  const half_t* ga1 = A + (size_t)(m0 + (2 * w + 1) * 16 + l15) * K + quad * 8;
  const half_t* gb0 = Bt + (size_t)(n0 + (2 * w + 0) * 16 + l15) * K + quad * 8;
  const half_t* gb1 = Bt + (size_t)(n0 + (2 * w + 1) * 16 + l15) * K + quad * 8;
  half_t* la0 = &Asl[(2 * w + 0) * 512];
  half_t* la1 = &Asl[(2 * w + 1) * 512];
  half_t* lb0 = &Bsl[(2 * w + 0) * 512];
  half_t* lb1 = &Bsl[(2 * w + 1) * 512];

  for (int k0 = 0; k0 < K; k0 += 32) {
    __syncthreads();
    load_lds16(ga0 + k0, la0);
    load_lds16(ga1 + k0, la1);
    load_lds16(gb0 + k0, lb0);
    load_lds16(gb1 + k0, lb1);
    __syncthreads();

    half8 af[4], bf[4];
#pragma unroll
    for (int i = 0; i < 4; i++) af[i] = *(half8*)&Asl[(wm * 4 + i) * 512 + lane * 8];
#pragma unroll
    for (int j = 0; j < 4; j++) bf[j] = *(half8*)&Bsl[(wn * 4 + j) * 512 + lane * 8];
#pragma unroll
    for (int i = 0; i < 4; i++)
#pragma unroll
      for (int j = 0; j < 4; j++)
        acc[i][j] = __builtin_amdgcn_mfma_f32_16x16x32_f16(af[i], bf[j], acc[i][j], 0, 0, 0);
  }

  const int rowbase = m0 + wm * 64;
  const int colbase = n0 + wn * 64;
  if (MODE == 0) {
#pragma unroll
    for (int i = 0; i < 4; i++)
#pragma unroll
      for (int j = 0; j < 4; j++)
#pragma unroll
        for (int r = 0; r < 4; r++)
          C[(size_t)(rowbase + i * 16 + quad * 4 + r) * N + colbase + j * 16 + l15] =
              acc[i][j][r];
  } else {
    const int which = colbase >> 10;            // 0=q,1=k,2=v (uniform per wave)
    const int h = (colbase & 1023) >> 6;        // uniform per wave
    const int b = rowbase >> 11;
    const int s0 = rowbase & (S_LEN - 1);
    const float scale = (which == 0) ? LOG2E : 1.0f;   // Q pre-scaled for exp2
    half_t* base = ((which == 0) ? Qo : (which == 1) ? Ko : Vo) +
                   (size_t)(b * NH + h) * S_LEN * DKV;
#pragma unroll
    for (int i = 0; i < 4; i++)
#pragma unroll
      for (int j = 0; j < 4; j++)
#pragma unroll
        for (int r = 0; r < 4; r++)
          base[(size_t)(s0 + i * 16 + quad * 4 + r) * DKV + j * 16 + l15] =
              (half_t)(acc[i][j][r] * scale);
  }
}

// ---------------------------------------------------------------------------
// fp16 MFMA flash attention, SPLIT-K over keys (2 partitions of 1024),
// S-TRANSPOSED register dataflow (NO P LDS round-trip):
//
//   S^T = K Q^T via mfma_16x16x32 with A=K-frag, B=Q-frag (fragments are
//   byte-identical to the old layout's loads, roles swapped).
//   C-layout of S^T: lane holds S[q=l15][key = nb*16 + quad*4 + r] — i.e.
//   each lane owns ONE query column. After exp2, p packs DIRECTLY into the
//   B-operand (k=quad*4+j, n=l15) of mfma_f32_16x16x16f16 computing
//   O^T = V^T P^T (A = Vt b64 fragments from the same swizzled Vts).
//
//   Consequences: Ps buffer + ones-column l-MFMAs deleted; softmax state
//   (m,l,al) is ONE scalar per lane; max/sum reduce = 15 local ops +
//   ds_swizzle(xor16) + shfl_xor(32). LDS 17 KB (was 25.6).
//   EXP2 domain throughout (Q pre-scaled by log2e; badd = log2e * bias).
// ---------------------------------------------------------------------------
__global__ __launch_bounds__(256) void attn_split(const half_t* __restrict__ Q,
                                                  const half_t* __restrict__ K,
                                                  const half_t* __restrict__ Vt,
                                                  const float* __restrict__ table,
                                                  float* __restrict__ Opart,
                                                  float* __restrict__ Mp,
                                                  float* __restrict__ Lp) {
  __shared__ half_t Ks[64 * 64];    // [key][d] swizzled (8-half units ^ row&7)
  __shared__ half_t Vts[64 * 64];   // [d][key] swizzled
  __shared__ float tb[32];
  __shared__ float badd[184];       // log2e * bias by clamp(delta,-91,91)+91

  const int tid = threadIdx.x;
  const int w = tid >> 6;
  const int lane = tid & 63;
  const int l15 = lane & 15;
  const int quad = lane >> 4;
  const int bh = blockIdx.y;
  const int h = bh & (NH - 1);
  const int part = blockIdx.x & 1;
  const int q0w = (blockIdx.x >> 1) * 64 + w * 16;

  if (tid < 32) tb[tid] = table[tid * NH + h] * LOG2E;
  __syncthreads();
  if (tid < 183) badd[tid] = tb[t5_bucket(tid - 91)];
  const float tb_neg = tb[15], tb_pos = tb[31];   // capped-region biases (scaled)

  // Q B-fragments (same bytes as ever): B[k=quad*8+j][n=l15] = Q[q0w+l15][...]
  half8 qf[2];
#pragma unroll
  for (int ks = 0; ks < 2; ks++)
    qf[ks] = *(const half8*)(Q + ((size_t)bh * S_LEN + q0w + l15) * DKV +
                             ks * 32 + quad * 8);

  // O^T accumulators: o[nb] holds O[q=l15][d = nb*16 + quad*4 + r]
  floatx4 o[4];
#pragma unroll
  for (int nb = 0; nb < 4; nb++) o[nb] = (floatx4){0.f, 0.f, 0.f, 0.f};
  float m = -1e30f, l = 0.0f;

  const int jr = tid >> 2;
  const int ub = (tid & 3) * 2;
  const int sw = jr & 7;
  // S^T A-frag (K rows): addr = key*64 + ((ks*4+quad)^(key&7))*8, key=nb*16+l15
  const int kv_rd0 = l15 * 64 + ((0 * 4 + quad) ^ (l15 & 7)) * 8;
  const int kv_rd1 = l15 * 64 + ((1 * 4 + quad) ^ (l15 & 7)) * 8;
  // PV A-frag (Vt rows, b64): row = nb*16+l15, in-row pos kt*16+quad*4
  //   unit = kt*2 + (quad>>1), half-offset (quad&1)*4
  const int q2h = quad >> 1, q2l = (quad & 1) * 4;

  const half_t* Kg = K + ((size_t)bh * S_LEN + part * 1024 + jr) * DKV + ub * 8;
  const half_t* Vg = Vt + ((size_t)bh * DKV + jr) * S_LEN + part * 1024 + ub * 8;
  int rel = part * 1024 - q0w;   // kc - q0w, wave-uniform

  for (int it = 0; it < 16; it++, rel += 64, Kg += 64 * DKV, Vg += 64) {
    __syncthreads();
    {
      half8 k0v = *(const half8*)(Kg);
      half8 k1v = *(const half8*)(Kg + 8);
      half8 v0v = *(const half8*)(Vg);
      half8 v1v = *(const half8*)(Vg + 8);
      *(half8*)&Ks[jr * 64 + ((ub + 0) ^ sw) * 8] = k0v;
      *(half8*)&Ks[jr * 64 + ((ub + 1) ^ sw) * 8] = k1v;
      *(half8*)&Vts[jr * 64 + ((ub + 0) ^ sw) * 8] = v0v;
      *(half8*)&Vts[jr * 64 + ((ub + 1) ^ sw) * 8] = v1v;
    }
    __syncthreads();

    // ---- S^T = K Q'^T : s[nb][r] = S[q=l15][key = nb*16+quad*4+r] ----
    floatx4 s[4];
#pragma unroll
    for (int nb = 0; nb < 4; nb++) {
      s[nb] = (floatx4){0.f, 0.f, 0.f, 0.f};
      s[nb] = __builtin_amdgcn_mfma_f32_16x16x32_f16(
          *(half8*)&Ks[nb * 1024 + kv_rd0], qf[0], s[nb], 0, 0, 0);
      s[nb] = __builtin_amdgcn_mfma_f32_16x16x32_f16(
          *(half8*)&Ks[nb * 1024 + kv_rd1], qf[1], s[nb], 0, 0, 0);
    }

    // ---- online softmax (lane owns one q; reduce over quads) ----
    float cm = fmaxf(fmaxf(fmaxf(s[0][0], s[0][1]), fmaxf(s[0][2], s[0][3])),
                     fmaxf(fmaxf(s[1][0], s[1][1]), fmaxf(s[1][2], s[1][3])));
    cm = fmaxf(cm, fmaxf(fmaxf(fmaxf(s[2][0], s[2][1]), fmaxf(s[2][2], s[2][3])),
                         fmaxf(fmaxf(s[3][0], s[3][1]), fmaxf(s[3][2], s[3][3]))));
    {
      int i = __builtin_amdgcn_ds_swizzle(__float_as_int(cm), 0x401F);  // xor 16
      cm = fmaxf(cm, __int_as_float(i));
      cm = fmaxf(cm, __shfl_xor(cm, 32));
    }
    float mn = fmaxf(m, cm);
    float al = exp2f(m - mn);
    m = mn;

    float lsum = 0.0f;
    halfx4 pvb[4];   // PV B-frags: pvb[kt][j] = p(key = kt*16 + quad*4 + j)
    if (rel >= 106 || rel <= -154) {
      const float sh = ((rel >= 106) ? tb_pos : tb_neg) - mn;
#pragma unroll
      for (int nb = 0; nb < 4; nb++)
#pragma unroll
        for (int r = 0; r < 4; r++) {
          float p = exp2f(s[nb][r] + sh);
          lsum += p;
          pvb[nb][r] = (half_t)p;
        }
    } else {
      const int db = rel + quad * 4 - l15 + 91;   // delta+91 at nb=0,r=0
#pragma unroll
      for (int nb = 0; nb < 4; nb++)
#pragma unroll
        for (int r = 0; r < 4; r++) {
          int idx = db + nb * 16 + r;
          idx = idx < 0 ? 0 : (idx > 182 ? 182 : idx);
          float p = exp2f(s[nb][r] - mn + badd[idx]);
          lsum += p;
          pvb[nb][r] = (half_t)p;
        }
    }
    {
      int i = __builtin_amdgcn_ds_swizzle(__float_as_int(lsum), 0x401F);
      lsum += __int_as_float(i);
      lsum += __shfl_xor(lsum, 32);
    }
    l = l * al + lsum;
#pragma unroll
    for (int nb = 0; nb < 4; nb++)
#pragma unroll
      for (int r = 0; r < 4; r++) o[nb][r] *= al;

    // ---- O^T += V^T P^T : 16 x mfma_16x16x16, A = Vt b64 frags ----
#pragma unroll
    for (int nb = 0; nb < 4; nb++) {
      const int vrow = (nb * 16 + l15);
      const int vsw = vrow & 7;
#pragma unroll
      for (int kt = 0; kt < 4; kt++) {
        halfx4 vf = *(halfx4*)&Vts[vrow * 64 + ((kt * 2 + q2h) ^ vsw) * 8 + q2l];
        o[nb] = __builtin_amdgcn_mfma_f32_16x16x16f16(vf, pvb[kt], o[nb], 0, 0, 0);
      }
    }
  }

  // ---- epilogue: lane q=l15 -> contiguous float4 stores per d-block ----
  {
    int row = bh * S_LEN + q0w + l15;   // bh*2048 + q
    float* op = Opart + (size_t)part * 4194304 + (size_t)row * 64;
#pragma unroll
    for (int nb = 0; nb < 4; nb++)
      *(float4*)(op + nb * 16 + quad * 4) =
          make_float4(o[nb][0], o[nb][1], o[nb][2], o[nb][3]);
    if (quad == 0) {
      Mp[part * 65536 + row] = m;
      Lp[part * 65536 + row] = l;
    }
  }
}

// ---------------------------------------------------------------------------
// Merge the 2 split-K partials (log2-domain m): exact combine, write X fp16.
// ---------------------------------------------------------------------------
__global__ __launch_bounds__(256) void attn_combine(const float* __restrict__ Opart,
                                                    const float* __restrict__ Mp,
                                                    const float* __restrict__ Lp,
                                                    half_t* __restrict__ X) {
  int idx = blockIdx.x * 256 + threadIdx.x;
  int row = idx >> 6;        // bh*2048 + q
  int d = idx & 63;
  float m0 = Mp[row], m1 = Mp[65536 + row];
  float l0 = Lp[row], l1 = Lp[65536 + row];
  float M = fmaxf(m0, m1);
  float a0 = exp2f(m0 - M), a1 = exp2f(m1 - M);
  float L = l0 * a0 + l1 * a1;
  float o = (Opart[(size_t)row * 64 + d] * a0 +
             Opart[4194304 + (size_t)row * 64 + d] * a1) / L;
  int bh = row >> 11, q = row & (S_LEN - 1);
  int b = bh >> 4, h = bh & (NH - 1);
  X[(size_t)(b * S_LEN + q) * DMODEL + h * DKV + d] = (half_t)o;
}

// ---------------------------------------------------------------------------
// kernel_launch
// ws layout (halves): Ah 4M (reused as Vt) | Wqt 3M | Wot 1M | Qh 4M | Kh 4M |
//   Vh 4M | Xh 4M | then f32: Opart 8.39M | Mp 131072 | Lp 131072  (~90 MB)
// ---------------------------------------------------------------------------
extern "C" void kernel_launch(void* const* d_in, const int* in_sizes, int n_in,
                              void* d_out, int out_size, void* d_ws, size_t ws_size,
                              hipStream_t stream) {
  const float* hidden = (const float*)d_in[0];
  const float* w_qkv = (const float*)d_in[1];
  const float* w_o = (const float*)d_in[2];
  const float* table = (const float*)d_in[3];

  float* attn_out = (float*)d_out;
  float* bias_out = (float*)d_out + 4194304;

  half_t* Ah  = (half_t*)d_ws;     // hidden fp16; reused as Vt after QKV GEMM
  half_t* Wqt = Ah + 4194304;      // [3072][1024]
  half_t* Wot = Wqt + 3145728;     // [1024][1024]
  half_t* Qh  = Wot + 1048576;     // [b,h,s,d], pre-scaled by log2e
  half_t* Kh  = Qh + 4194304;      // [b,h,s,d]
  half_t* Vh  = Kh + 4194304;      // [b,h,s,d]
  half_t* Xh  = Vh + 4194304;      // [4096][1024]
  half_t* Vth = Ah;                // [b,h,d,s] (aliases Ah; Ah dead by then)
  float* Opart = (float*)(Xh + 4194304);   // 2 x 4,194,304 f32
  float* Mpp   = Opart + 8388608;          // 2 x 65536
  float* Lpp   = Mpp + 131072;             // 2 x 65536

  // prep (r7 shape): casts + weight transposes + position_bias
  cast_f2h<<<4096, 256, 0, stream>>>(hidden, Ah);
  transpose_cast<<<dim3(3072 / 32, 1024 / 32), 256, 0, stream>>>(w_qkv, Wqt, 1024, 3072);
  transpose_cast<<<dim3(1024 / 32, 1024 / 32), 256, 0, stream>>>(w_o, Wot, 1024, 1024);
  bias_kernel<<<NH * S_LEN, 256, 0, stream>>>(table, bias_out);

  // QKV projection (fp16 MFMA; Q epilogue pre-scales by log2e)
  hgemm128<1><<<dim3(3072 / 128, 4096 / 128), 256, 0, stream>>>(
      Ah, Wqt, nullptr, Qh, Kh, Vh, 4096, 3072, 1024);

  // V -> Vt transpose (Ah is dead now; Vt aliases it)
  vtrans<<<dim3(S_LEN / 64, BATCH * NH), 256, 0, stream>>>(Vh, Vth);

  // split-K fp16 MFMA flash attention (S^T dataflow, exp2) -> partials -> Xh
  attn_split<<<dim3((S_LEN / 64) * 2, BATCH * NH), 256, 0, stream>>>(
      Qh, Kh, Vth, table, Opart, Mpp, Lpp);
  attn_combine<<<4194304 / 256, 256, 0, stream>>>(Opart, Mpp, Lpp, Xh);

  // output projection -> d_out fp32
  hgemm128<0><<<dim3(1024 / 128, 4096 / 128), 256, 0, stream>>>(
      Xh, Wot, attn_out, nullptr, nullptr, nullptr, 4096, 1024, 1024);
}